// Round 8
// baseline (480.285 us; speedup 1.0000x reference)
//
#include <hip/hip_runtime.h>
#include <stdint.h>

#define E 384
#define SEQ 4096
#define BATCH 4
#define NHEAD 6
#define HD 64
#define M_TOK 16384
#define QKVN 1152
#define FFH 1536

typedef __bf16 bf16x8 __attribute__((ext_vector_type(8)));
typedef __bf16 bf16x4 __attribute__((ext_vector_type(4)));
typedef float floatx4 __attribute__((ext_vector_type(4)));
typedef unsigned int uintx2 __attribute__((ext_vector_type(2)));
typedef unsigned int uintx4 __attribute__((ext_vector_type(4)));

__device__ __forceinline__ unsigned short f2b(float f) {
  unsigned int u = __builtin_bit_cast(unsigned int, f);
  u += 0x7fffu + ((u >> 16) & 1u);
  return (unsigned short)(u >> 16);
}

__device__ __forceinline__ void gl_lds16(const void* g, void* l) {
  __builtin_amdgcn_global_load_lds((__attribute__((address_space(1))) void*)g,
                                   (__attribute__((address_space(3))) void*)l,
                                   16, 0, 0);
}

__device__ __forceinline__ floatx4 mfma16(bf16x8 a, bf16x8 b, floatx4 c) {
  return __builtin_amdgcn_mfma_f32_16x16x32_bf16(a, b, c, 0, 0, 0);
}

// ---------------- weight transpose+convert: fp32 (K,N) -> bf16 (N,K) ----------------
// Also zeroes condp (cond_proj output) so the later atomic kernel can accumulate.
__global__ __launch_bounds__(256) void prep_weights(
    const float* __restrict__ wq, const float* __restrict__ wk,
    const float* __restrict__ wv, const float* __restrict__ wo,
    const float* __restrict__ f1, const float* __restrict__ f2,
    unsigned short* __restrict__ qkv_t, unsigned short* __restrict__ wo_t,
    unsigned short* __restrict__ f1_t, unsigned short* __restrict__ f2_t,
    float* __restrict__ condp) {
  int tid = blockIdx.x * 256 + threadIdx.x;
  const int R0 = QKVN * E;
  const int R1 = E * E;
  const int R2 = FFH * E;
  if (tid < 6 * BATCH * E) condp[tid] = 0.f;
  if (tid < R0) {
    int n = tid / E, k = tid - n * E;
    float v = (n < E) ? wq[k * E + n] : (n < 2 * E) ? wk[k * E + n - E] : wv[k * E + n - 2 * E];
    qkv_t[tid] = f2b(v);
  } else if (tid < R0 + R1) {
    int id = tid - R0;
    int n = id / E, k = id - n * E;
    wo_t[id] = f2b(wo[k * E + n]);
  } else if (tid < R0 + R1 + R2) {
    int id = tid - (R0 + R1);
    int n = id / E, k = id - n * E;
    f1_t[id] = f2b(f1[k * FFH + n]);
  } else {
    int id = tid - (R0 + R1 + R2);
    int n = id / FFH, k = id - n * FFH;
    f2_t[id] = f2b(f2[k * E + n]);
  }
}

// ---------------- cond projections: k-split x4, atomic accumulate ----------------
__global__ __launch_bounds__(256) void cond_proj(
    const float* __restrict__ cond,
    const float* __restrict__ w0, const float* __restrict__ b0,
    const float* __restrict__ w1, const float* __restrict__ b1,
    const float* __restrict__ w2, const float* __restrict__ b2,
    const float* __restrict__ w3, const float* __restrict__ b3,
    const float* __restrict__ w4, const float* __restrict__ b4,
    const float* __restrict__ w5, const float* __restrict__ b5,
    float* __restrict__ outp) {
  int tid = blockIdx.x * 256 + threadIdx.x;  // 0..36863
  int id = tid % (6 * BATCH * E);            // output index (lanes -> consecutive o)
  int ks = tid / (6 * BATCH * E);            // k-slice 0..3
  int j = id / (BATCH * E);
  int rem = id - j * (BATCH * E);
  int b = rem / E, o = rem - b * E;
  const float* w; const float* bb;
  switch (j) {
    case 0: w = w0; bb = b0; break;
    case 1: w = w1; bb = b1; break;
    case 2: w = w2; bb = b2; break;
    case 3: w = w3; bb = b3; break;
    case 4: w = w4; bb = b4; break;
    default: w = w5; bb = b5; break;
  }
  float acc = (ks == 0) ? bb[o] : 0.f;
  const float* c = cond + b * E;
#pragma unroll 8
  for (int i = ks * 96; i < ks * 96 + 96; i++) acc += c[i] * w[i * E + o];
  atomicAdd(&outp[id], acc);
}

// ---------------- LayerNorm + AdaLN modulate -> bf16 ----------------
__global__ __launch_bounds__(256) void ln_mod(
    const float* __restrict__ in, const float* __restrict__ lw,
    const float* __restrict__ lb, const float* __restrict__ gamma,
    const float* __restrict__ beta, unsigned short* __restrict__ outb) {
  int lane = threadIdx.x & 63, wave = threadIdx.x >> 6;
  int m = blockIdx.x * 4 + wave;
  int b = m >> 12;
  const float* row = in + (size_t)m * E;
  float v[6], s = 0.f, s2 = 0.f;
#pragma unroll
  for (int i = 0; i < 6; i++) {
    float xv = row[lane + i * 64];
    v[i] = xv; s += xv; s2 += xv * xv;
  }
#pragma unroll
  for (int off = 32; off; off >>= 1) {
    s += __shfl_xor(s, off, 64);
    s2 += __shfl_xor(s2, off, 64);
  }
  float mean = s * (1.f / E);
  float var = s2 * (1.f / E) - mean * mean;
  float inv = rsqrtf(var + 1e-5f);
#pragma unroll
  for (int i = 0; i < 6; i++) {
    int e = lane + i * 64;
    float y = (v[i] - mean) * inv * lw[e] + lb[e];
    float g = gamma[b * E + e], be = beta[b * E + e];
    outb[(size_t)m * E + e] = f2b(y * (1.f + g) + be);
  }
}

// ---------------- bf16 MFMA GEMM, Bt layout (N,K), 128x128 tile, BK=32, dbuf ----------
template <int EPI>
__global__ __launch_bounds__(256) void gemm_bt(
    const unsigned short* __restrict__ A, const unsigned short* __restrict__ Bt,
    const float* __restrict__ bias, const float* __restrict__ alpha,
    const float* __restrict__ resid, float* __restrict__ outf,
    unsigned short* __restrict__ outb, int N, int K) {
  __shared__ __align__(16) unsigned short As[2][128 * 32];
  __shared__ __align__(16) unsigned short Bs[2][128 * 32];
  int t = threadIdx.x, lane = t & 63, wave = t >> 6;
  int m0 = blockIdx.y * 128, n0 = blockIdx.x * 128;
  int m15 = lane & 15, quad = lane >> 4;

  floatx4 acc[4][4];
  floatx4 vz = {0.f, 0.f, 0.f, 0.f};
#pragma unroll
  for (int i = 0; i < 4; i++)
#pragma unroll
    for (int j = 0; j < 4; j++) acc[i][j] = vz;

  int wm = (wave >> 1) * 64, wn = (wave & 1) * 64;
  int gsw = (quad ^ (m15 & 3)) * 8;

  auto stage = [&](int k0, int sb) {
#pragma unroll
    for (int c = 0; c < 2; c++) {
      int t2 = c * 256 + t;
      int r = t2 >> 2;
      int G = (t2 & 3) ^ (r & 3);
      gl_lds16(A + (size_t)(m0 + r) * K + k0 + G * 8, &As[sb][(size_t)(c * 256 + wave * 64) * 8]);
      gl_lds16(Bt + (size_t)(n0 + r) * K + k0 + G * 8, &Bs[sb][(size_t)(c * 256 + wave * 64) * 8]);
    }
  };

  stage(0, 0);
  __syncthreads();

  int nsteps = K >> 5;
  for (int s = 0; s < nsteps; s++) {
    int cur = s & 1;
    if (s + 1 < nsteps) stage((s + 1) << 5, cur ^ 1);
    bf16x8 af[4], bf[4];
#pragma unroll
    for (int i = 0; i < 4; i++) {
      af[i] = *(const bf16x8*)&As[cur][(wm + i * 16 + m15) * 32 + gsw];
      bf[i] = *(const bf16x8*)&Bs[cur][(wn + i * 16 + m15) * 32 + gsw];
    }
#pragma unroll
    for (int mi = 0; mi < 4; mi++)
#pragma unroll
      for (int ni = 0; ni < 4; ni++) acc[mi][ni] = mfma16(af[mi], bf[ni], acc[mi][ni]);
    __syncthreads();
  }

  int rbase = quad * 4;
#pragma unroll
  for (int mi = 0; mi < 4; mi++) {
#pragma unroll
    for (int ni = 0; ni < 4; ni++) {
#pragma unroll
      for (int r = 0; r < 4; r++) {
        int row = m0 + wm + mi * 16 + rbase + r;
        int col = n0 + wn + ni * 16 + m15;
        float v = acc[mi][ni][r];
        if (EPI == 0) {
          outb[(size_t)row * N + col] = f2b(v);
        } else if (EPI == 1) {
          int b = row >> 12;
          size_t o = (size_t)row * E + col;
          outf[o] = resid[o] + v * alpha[b * E + col];
        } else if (EPI == 2) {
          v += bias[col];
          outb[(size_t)row * N + col] = f2b(v > 0.f ? v : 0.f);
        } else {
          int b = row >> 12;
          size_t o = (size_t)row * E + col;
          outf[o] = outf[o] + (v + bias[col]) * alpha[b * E + col];
        }
      }
    }
  }
}

// ---------------- bf16 MFMA GEMM, 64x128 tile, double-buffered ----------------
template <int EPI>
__global__ __launch_bounds__(256) void gemm64(
    const unsigned short* __restrict__ A, const unsigned short* __restrict__ Bt,
    const float* __restrict__ bias, const float* __restrict__ alpha,
    const float* __restrict__ resid, float* __restrict__ outf,
    unsigned short* __restrict__ outb, int N, int K) {
  __shared__ __align__(16) unsigned short As[2][64 * 32];
  __shared__ __align__(16) unsigned short Bs[2][128 * 32];
  int t = threadIdx.x, lane = t & 63, wave = t >> 6;
  int m0 = blockIdx.y * 64, n0 = blockIdx.x * 128;
  int m15 = lane & 15, quad = lane >> 4;

  floatx4 acc[4][2];
  floatx4 vz = {0.f, 0.f, 0.f, 0.f};
#pragma unroll
  for (int i = 0; i < 4; i++)
#pragma unroll
    for (int j = 0; j < 2; j++) acc[i][j] = vz;

  int wn = wave * 32;
  int gsw = (quad ^ (m15 & 3)) * 8;

  auto stage = [&](int k0, int sb) {
    {
      int r = t >> 2;
      int G = (t & 3) ^ (r & 3);
      gl_lds16(A + (size_t)(m0 + r) * K + k0 + G * 8, &As[sb][(size_t)(wave * 64) * 8]);
    }
#pragma unroll
    for (int c = 0; c < 2; c++) {
      int t2 = c * 256 + t;
      int r = t2 >> 2;
      int G = (t2 & 3) ^ (r & 3);
      gl_lds16(Bt + (size_t)(n0 + r) * K + k0 + G * 8, &Bs[sb][(size_t)(c * 256 + wave * 64) * 8]);
    }
  };

  stage(0, 0);
  __syncthreads();

  int nsteps = K >> 5;
  for (int s = 0; s < nsteps; s++) {
    int cur = s & 1;
    if (s + 1 < nsteps) stage((s + 1) << 5, cur ^ 1);
    bf16x8 af[4], bf[2];
#pragma unroll
    for (int i = 0; i < 4; i++) af[i] = *(const bf16x8*)&As[cur][(i * 16 + m15) * 32 + gsw];
#pragma unroll
    for (int j = 0; j < 2; j++) bf[j] = *(const bf16x8*)&Bs[cur][(wn + j * 16 + m15) * 32 + gsw];
#pragma unroll
    for (int mi = 0; mi < 4; mi++)
#pragma unroll
      for (int ni = 0; ni < 2; ni++) acc[mi][ni] = mfma16(af[mi], bf[ni], acc[mi][ni]);
    __syncthreads();
  }

  int rbase = quad * 4;
#pragma unroll
  for (int mi = 0; mi < 4; mi++) {
#pragma unroll
    for (int ni = 0; ni < 2; ni++) {
#pragma unroll
      for (int r = 0; r < 4; r++) {
        int row = m0 + mi * 16 + rbase + r;
        int col = n0 + wn + ni * 16 + m15;
        float v = acc[mi][ni][r];
        if (EPI == 1) {
          int b = row >> 12;
          size_t o = (size_t)row * E + col;
          outf[o] = resid[o] + v * alpha[b * E + col];
        } else {
          int b = row >> 12;
          size_t o = (size_t)row * E + col;
          outf[o] = outf[o] + (v + bias[col]) * alpha[b * E + col];
        }
      }
    }
  }
}

// ---------------- flash attention v6b: Q-LDS aliased over 2nd K/V buffer ----------
// Identical math/dataflow to v5 (verified). Qs (16KB) is dead after the prologue
// (Q lives in registers), so it aliases the buf=1 K/V region: LDS 48KB -> 32KB,
// 3 -> 4 blocks/CU. LDS addressing via integer offsets into one smem array
// (pointer-array of LDS addrs triggers an unsupported addrspacecast initializer).
// Layout: [0:4096) Ks0, [4096:8192) Vt0, [8192:12288) Ks1 (=Qs lo), [12288:16384) Vt1.
__global__ __launch_bounds__(256) void flash_attn(const unsigned short* __restrict__ qkv,
                                                  unsigned short* __restrict__ outb) {
  __shared__ __align__(16) unsigned short smem[16384];  // 32 KB
  int t = threadIdx.x, lane = t & 63, wave = t >> 6;
  int m15 = lane & 15, quad = lane >> 4;
  int q0 = blockIdx.x * 128;
  int bh = blockIdx.y;
  int b = bh / NHEAD, h = bh - b * NHEAD;
  const unsigned short* qp = qkv + (size_t)b * SEQ * QKVN + h * HD;
  const unsigned short* kp = qp + E;
  const unsigned short* vp = qp + 2 * E;
  int kpr = t & 31, dg = t >> 5;

  auto stageK = [&](int kb0, int koff) {
#pragma unroll
    for (int c = 0; c < 2; c++) {
      int slot = c * 256 + t;
      int kr = slot >> 3, s = slot & 7;
      int g = s ^ (kr & 7);
      gl_lds16(kp + (size_t)(kb0 + kr) * QKVN + g * 8,
               smem + koff + (size_t)(c * 256 + wave * 64) * 8);
    }
  };
  auto loadV = [&](int kb0, int4& r0, int4& r1) {
    r0 = *(const int4*)(vp + (size_t)(kb0 + 2 * kpr) * QKVN + dg * 8);
    r1 = *(const int4*)(vp + (size_t)(kb0 + 2 * kpr + 1) * QKVN + dg * 8);
  };
  auto writeVt = [&](int voff, int4 r0, int4 r1) {
    const unsigned short* u0 = (const unsigned short*)&r0;
    const unsigned short* u1 = (const unsigned short*)&r1;
    int kg = kpr >> 2, pos = kpr & 3;
#pragma unroll
    for (int i = 0; i < 8; i++) {
      int d = dg * 8 + i;
      *(unsigned int*)&smem[voff + 2 * (d * 32 + ((kg ^ i ^ dg) & 7) * 4 + pos)] =
          (unsigned int)u0[i] | ((unsigned int)u1[i] << 16);
    }
  };

  // prologue: stage Q into alias region [8192:16384) + K0; V0 -> regs
#pragma unroll
  for (int c = 0; c < 4; c++) {
    int slot = c * 256 + t;
    int qr = slot >> 3, s = slot & 7;
    int g = s ^ (qr & 7);
    gl_lds16(qp + (size_t)(q0 + qr) * QKVN + g * 8,
             smem + 8192 + (size_t)(c * 256 + wave * 64) * 8);
  }
  stageK(0, 0);
  int4 va, vb;
  loadV(0, va, vb);
  __syncthreads();  // Q + K0 resident; va/vb in regs
  writeVt(4096, va, vb);

  // Q frags, pre-scaled by 1/sqrt(HD) * log2(e)
  const float QSCALE = 0.125f * 1.44269504f;
  bf16x8 qf[2][2];
#pragma unroll
  for (int mt = 0; mt < 2; mt++) {
    int qr = wave * 32 + mt * 16 + m15;
#pragma unroll
    for (int dh = 0; dh < 2; dh++) {
      bf16x8 v = *(const bf16x8*)&smem[8192 + qr * 64 + (((dh * 4 + quad) ^ (m15 & 7)) * 8)];
#pragma unroll
      for (int i = 0; i < 8; i++) v[i] = (__bf16)((float)v[i] * QSCALE);
      qf[mt][dh] = v;
    }
  }
  __syncthreads();  // all waves consumed Qs (and Vt0 visible) before loop stages buf 1

  float lsum[2] = {0.f, 0.f};
  floatx4 of[2][4];
  floatx4 vz = {0.f, 0.f, 0.f, 0.f};
#pragma unroll
  for (int mt = 0; mt < 2; mt++)
#pragma unroll
    for (int dt = 0; dt < 4; dt++) of[mt][dt] = vz;

  int buf = 0;
  for (int kb0 = 0; kb0 < SEQ; kb0 += 64) {
    int kcur = buf ? 8192 : 0, vcur = kcur + 4096;
    int knxt = buf ? 0 : 8192, vnxt = knxt + 4096;
    bf16x8 kf[4][2], vf[4][2];
#pragma unroll
    for (int kt = 0; kt < 4; kt++)
#pragma unroll
      for (int dh = 0; dh < 2; dh++)
        kf[kt][dh] =
            *(const bf16x8*)&smem[kcur + (kt * 16 + m15) * 64 + (((dh * 4 + quad) ^ (m15 & 7)) * 8)];
#pragma unroll
    for (int dt = 0; dt < 4; dt++)
#pragma unroll
      for (int kc = 0; kc < 2; kc++) {
        int d7 = m15 & 7, d3 = dt * 2 + (m15 >> 3);
        vf[dt][kc] = *(const bf16x8*)&smem[vcur + (dt * 16 + m15) * 64 +
                                           ((((kc * 4 + quad) ^ d7 ^ d3) & 7) * 8)];
      }

    int nkb = (kb0 + 64) & (SEQ - 1);
    stageK(nkb, knxt);
    loadV(nkb, va, vb);

#pragma unroll
    for (int mt = 0; mt < 2; mt++) {
      floatx4 st[4];
#pragma unroll
      for (int kt = 0; kt < 4; kt++) {
        st[kt] = vz;
#pragma unroll
        for (int dh = 0; dh < 2; dh++) st[kt] = mfma16(kf[kt][dh], qf[mt][dh], st[kt]);
      }
      uintx2 pk[4];
      float lp = 0.f;
#pragma unroll
      for (int kt = 0; kt < 4; kt++) {
        floatx4 p;
#pragma unroll
        for (int r = 0; r < 4; r++) {
          p[r] = __builtin_amdgcn_exp2f(st[kt][r]);
          lp += p[r];
        }
        bf16x4 pb = __builtin_convertvector(p, bf16x4);
        pk[kt] = __builtin_bit_cast(uintx2, pb);
      }
      lsum[mt] += lp;

      int L0 = ((quad & 1) << 5) + m15;
      bool hi = (quad >> 1) != 0;
#pragma unroll
      for (int kc = 0; kc < 2; kc++) {
        int a0 = __shfl((int)pk[kc * 2].x, L0, 64);
        int a1 = __shfl((int)pk[kc * 2].y, L0, 64);
        int a2 = __shfl((int)pk[kc * 2].x, L0 + 16, 64);
        int a3 = __shfl((int)pk[kc * 2].y, L0 + 16, 64);
        int b0 = __shfl((int)pk[kc * 2 + 1].x, L0, 64);
        int b1 = __shfl((int)pk[kc * 2 + 1].y, L0, 64);
        int b2 = __shfl((int)pk[kc * 2 + 1].x, L0 + 16, 64);
        int b3 = __shfl((int)pk[kc * 2 + 1].y, L0 + 16, 64);
        uintx4 sel;
        sel.x = (unsigned)(hi ? b0 : a0);
        sel.y = (unsigned)(hi ? b1 : a1);
        sel.z = (unsigned)(hi ? b2 : a2);
        sel.w = (unsigned)(hi ? b3 : a3);
        bf16x8 pB = __builtin_bit_cast(bf16x8, sel);
#pragma unroll
        for (int dt = 0; dt < 4; dt++) of[mt][dt] = mfma16(vf[dt][kc], pB, of[mt][dt]);
      }
    }

    writeVt(vnxt, va, vb);
    __syncthreads();
    buf ^= 1;
  }

#pragma unroll
  for (int mt = 0; mt < 2; mt++) {
    lsum[mt] += __shfl_xor(lsum[mt], 16, 64);
    lsum[mt] += __shfl_xor(lsum[mt], 32, 64);
    float inv = 1.f / lsum[mt];
    int q = q0 + wave * 32 + mt * 16 + m15;
    unsigned short* orow = outb + (size_t)(b * SEQ + q) * E + h * HD;
#pragma unroll
    for (int dt = 0; dt < 4; dt++) {
      floatx4 o;
#pragma unroll
      for (int r = 0; r < 4; r++) o[r] = of[mt][dt][r] * inv;
      bf16x4 ob = __builtin_convertvector(o, bf16x4);
      *(uintx2*)&orow[dt * 16 + quad * 4] = __builtin_bit_cast(uintx2, ob);
    }
  }
}

extern "C" void kernel_launch(void* const* d_in, const int* in_sizes, int n_in,
                              void* d_out, int out_size, void* d_ws, size_t ws_size,
                              hipStream_t stream) {
  const float* x     = (const float*)d_in[0];
  const float* cond  = (const float*)d_in[1];
  const float* g1_w  = (const float*)d_in[2];  const float* g1_b  = (const float*)d_in[3];
  const float* be1_w = (const float*)d_in[4];  const float* be1_b = (const float*)d_in[5];
  const float* a1_w  = (const float*)d_in[6];  const float* a1_b  = (const float*)d_in[7];
  const float* g2_w  = (const float*)d_in[8];  const float* g2_b  = (const float*)d_in[9];
  const float* be2_w = (const float*)d_in[10]; const float* be2_b = (const float*)d_in[11];
  const float* a2_w  = (const float*)d_in[12]; const float* a2_b  = (const float*)d_in[13];
  const float* ln1_w = (const float*)d_in[14]; const float* ln1_b = (const float*)d_in[15];
  const float* ln2_w = (const float*)d_in[16]; const float* ln2_b = (const float*)d_in[17];
  const float* wq    = (const float*)d_in[18]; const float* wk    = (const float*)d_in[19];
  const float* wv    = (const float*)d_in[20]; const float* wo    = (const float*)d_in[21];
  const float* ff1_w = (const float*)d_in[22]; const float* ff1_b = (const float*)d_in[23];
  const float* ff2_w = (const float*)d_in[24]; const float* ff2_b = (const float*)d_in[25];
  float* out = (float*)d_out;

  char* ws = (char*)d_ws;
  size_t off = 0;
  auto alloc = [&](size_t bytes) -> void* {
    void* p = ws + off;
    off += (bytes + 255) & ~(size_t)255;
    return p;
  };
  float* condp            = (float*)alloc((size_t)6 * BATCH * E * 4);
  unsigned short* wqkv_t  = (unsigned short*)alloc((size_t)QKVN * E * 2);
  unsigned short* wo_t    = (unsigned short*)alloc((size_t)E * E * 2);
  unsigned short* ff1_t   = (unsigned short*)alloc((size_t)FFH * E * 2);
  unsigned short* ff2_t   = (unsigned short*)alloc((size_t)E * FFH * 2);
  unsigned short* ymod    = (unsigned short*)alloc((size_t)M_TOK * E * 2);
  unsigned short* qkvbuf  = (unsigned short*)alloc((size_t)M_TOK * QKVN * 2);
  unsigned short* attnout = (unsigned short*)alloc((size_t)M_TOK * E * 2);
  unsigned short* hbuf    = (unsigned short*)alloc((size_t)M_TOK * FFH * 2);

  float* gamma1 = condp;            float* beta1 = condp + 1536;
  float* alpha1 = condp + 3072;     float* gamma2 = condp + 4608;
  float* beta2 = condp + 6144;      float* alpha2 = condp + 7680;

  prep_weights<<<6912, 256, 0, stream>>>(wq, wk, wv, wo, ff1_w, ff2_w,
                                         wqkv_t, wo_t, ff1_t, ff2_t, condp);
  cond_proj<<<144, 256, 0, stream>>>(cond, g1_w, g1_b, be1_w, be1_b, a1_w, a1_b,
                                     g2_w, g2_b, be2_w, be2_b, a2_w, a2_b, condp);
  ln_mod<<<4096, 256, 0, stream>>>(x, ln1_w, ln1_b, gamma1, beta1, ymod);
  gemm_bt<0><<<dim3(QKVN / 128, M_TOK / 128), 256, 0, stream>>>(
      ymod, wqkv_t, nullptr, nullptr, nullptr, nullptr, qkvbuf, QKVN, E);
  flash_attn<<<dim3(SEQ / 128, BATCH * NHEAD), 256, 0, stream>>>(qkvbuf, attnout);
  gemm64<1><<<dim3(E / 128, M_TOK / 64), 256, 0, stream>>>(
      attnout, wo_t, nullptr, alpha1, x, out, nullptr, E, E);
  ln_mod<<<4096, 256, 0, stream>>>(out, ln2_w, ln2_b, gamma2, beta2, ymod);
  gemm_bt<2><<<dim3(FFH / 128, M_TOK / 128), 256, 0, stream>>>(
      ymod, ff1_t, ff1_b, nullptr, nullptr, nullptr, hbuf, FFH, E);
  gemm64<3><<<dim3(E / 128, M_TOK / 64), 256, 0, stream>>>(
      hbuf, ff2_t, ff2_b, alpha2, nullptr, out, nullptr, E, FFH);
}

// Round 10
// 427.402 us; speedup vs baseline: 1.1237x; 1.1237x over previous
//
#include <hip/hip_runtime.h>
#include <stdint.h>

#define E 384
#define SEQ 4096
#define BATCH 4
#define NHEAD 6
#define HD 64
#define M_TOK 16384
#define QKVN 1152
#define FFH 1536

typedef __bf16 bf16x8 __attribute__((ext_vector_type(8)));
typedef __bf16 bf16x4 __attribute__((ext_vector_type(4)));
typedef float floatx4 __attribute__((ext_vector_type(4)));
typedef unsigned int uintx2 __attribute__((ext_vector_type(2)));
typedef short short4v __attribute__((ext_vector_type(4)));

__device__ __forceinline__ unsigned short f2b(float f) {
  unsigned int u = __builtin_bit_cast(unsigned int, f);
  u += 0x7fffu + ((u >> 16) & 1u);
  return (unsigned short)(u >> 16);
}

__device__ __forceinline__ void gl_lds16(const void* g, void* l) {
  __builtin_amdgcn_global_load_lds((__attribute__((address_space(1))) void*)g,
                                   (__attribute__((address_space(3))) void*)l,
                                   16, 0, 0);
}

__device__ __forceinline__ floatx4 mfma16(bf16x8 a, bf16x8 b, floatx4 c) {
  return __builtin_amdgcn_mfma_f32_16x16x32_bf16(a, b, c, 0, 0, 0);
}

// K=16 bf16 MFMA (PV path): A/B = 4 bf16 per lane (k = quad*4+i).
// Body guarded: HIP's host pass parses __device__ bodies but lacks the builtin.
__device__ __forceinline__ floatx4 mfma16k16(short4v a, short4v b, floatx4 c) {
#if defined(__HIP_DEVICE_COMPILE__)
  return __builtin_amdgcn_mfma_f32_16x16x16bf16_1k(a, b, c, 0, 0, 0);
#else
  return c;
#endif
}

// ---------------- weight transpose+convert: fp32 (K,N) -> bf16 (N,K) ----------------
__global__ __launch_bounds__(256) void prep_weights(
    const float* __restrict__ wq, const float* __restrict__ wk,
    const float* __restrict__ wv, const float* __restrict__ wo,
    const float* __restrict__ f1, const float* __restrict__ f2,
    unsigned short* __restrict__ qkv_t, unsigned short* __restrict__ wo_t,
    unsigned short* __restrict__ f1_t, unsigned short* __restrict__ f2_t,
    float* __restrict__ condp) {
  int tid = blockIdx.x * 256 + threadIdx.x;
  const int R0 = QKVN * E;
  const int R1 = E * E;
  const int R2 = FFH * E;
  if (tid < 6 * BATCH * E) condp[tid] = 0.f;
  if (tid < R0) {
    int n = tid / E, k = tid - n * E;
    float v = (n < E) ? wq[k * E + n] : (n < 2 * E) ? wk[k * E + n - E] : wv[k * E + n - 2 * E];
    qkv_t[tid] = f2b(v);
  } else if (tid < R0 + R1) {
    int id = tid - R0;
    int n = id / E, k = id - n * E;
    wo_t[id] = f2b(wo[k * E + n]);
  } else if (tid < R0 + R1 + R2) {
    int id = tid - (R0 + R1);
    int n = id / E, k = id - n * E;
    f1_t[id] = f2b(f1[k * FFH + n]);
  } else {
    int id = tid - (R0 + R1 + R2);
    int n = id / FFH, k = id - n * FFH;
    f2_t[id] = f2b(f2[k * E + n]);
  }
}

// ---------------- cond projections: k-split x4, atomic accumulate ----------------
__global__ __launch_bounds__(256) void cond_proj(
    const float* __restrict__ cond,
    const float* __restrict__ w0, const float* __restrict__ b0,
    const float* __restrict__ w1, const float* __restrict__ b1,
    const float* __restrict__ w2, const float* __restrict__ b2,
    const float* __restrict__ w3, const float* __restrict__ b3,
    const float* __restrict__ w4, const float* __restrict__ b4,
    const float* __restrict__ w5, const float* __restrict__ b5,
    float* __restrict__ outp) {
  int tid = blockIdx.x * 256 + threadIdx.x;
  int id = tid % (6 * BATCH * E);
  int ks = tid / (6 * BATCH * E);
  int j = id / (BATCH * E);
  int rem = id - j * (BATCH * E);
  int b = rem / E, o = rem - b * E;
  const float* w; const float* bb;
  switch (j) {
    case 0: w = w0; bb = b0; break;
    case 1: w = w1; bb = b1; break;
    case 2: w = w2; bb = b2; break;
    case 3: w = w3; bb = b3; break;
    case 4: w = w4; bb = b4; break;
    default: w = w5; bb = b5; break;
  }
  float acc = (ks == 0) ? bb[o] : 0.f;
  const float* c = cond + b * E;
#pragma unroll 8
  for (int i = ks * 96; i < ks * 96 + 96; i++) acc += c[i] * w[i * E + o];
  atomicAdd(&outp[id], acc);
}

// ---------------- LayerNorm + AdaLN modulate -> bf16 ----------------
__global__ __launch_bounds__(256) void ln_mod(
    const float* __restrict__ in, const float* __restrict__ lw,
    const float* __restrict__ lb, const float* __restrict__ gamma,
    const float* __restrict__ beta, unsigned short* __restrict__ outb) {
  int lane = threadIdx.x & 63, wave = threadIdx.x >> 6;
  int m = blockIdx.x * 4 + wave;
  int b = m >> 12;
  const float* row = in + (size_t)m * E;
  float v[6], s = 0.f, s2 = 0.f;
#pragma unroll
  for (int i = 0; i < 6; i++) {
    float xv = row[lane + i * 64];
    v[i] = xv; s += xv; s2 += xv * xv;
  }
#pragma unroll
  for (int off = 32; off; off >>= 1) {
    s += __shfl_xor(s, off, 64);
    s2 += __shfl_xor(s2, off, 64);
  }
  float mean = s * (1.f / E);
  float var = s2 * (1.f / E) - mean * mean;
  float inv = rsqrtf(var + 1e-5f);
#pragma unroll
  for (int i = 0; i < 6; i++) {
    int e = lane + i * 64;
    float y = (v[i] - mean) * inv * lw[e] + lb[e];
    float g = gamma[b * E + e], be = beta[b * E + e];
    outb[(size_t)m * E + e] = f2b(y * (1.f + g) + be);
  }
}

// ---------------- bf16 MFMA GEMM, Bt layout (N,K), 128x128 tile, BK=32, dbuf ----------
template <int EPI>
__global__ __launch_bounds__(256) void gemm_bt(
    const unsigned short* __restrict__ A, const unsigned short* __restrict__ Bt,
    const float* __restrict__ bias, const float* __restrict__ alpha,
    const float* __restrict__ resid, float* __restrict__ outf,
    unsigned short* __restrict__ outb, int N, int K) {
  __shared__ __align__(16) unsigned short As[2][128 * 32];
  __shared__ __align__(16) unsigned short Bs[2][128 * 32];
  int t = threadIdx.x, lane = t & 63, wave = t >> 6;
  int m0 = blockIdx.y * 128, n0 = blockIdx.x * 128;
  int m15 = lane & 15, quad = lane >> 4;

  floatx4 acc[4][4];
  floatx4 vz = {0.f, 0.f, 0.f, 0.f};
#pragma unroll
  for (int i = 0; i < 4; i++)
#pragma unroll
    for (int j = 0; j < 4; j++) acc[i][j] = vz;

  int wm = (wave >> 1) * 64, wn = (wave & 1) * 64;
  int gsw = (quad ^ (m15 & 3)) * 8;

  auto stage = [&](int k0, int sb) {
#pragma unroll
    for (int c = 0; c < 2; c++) {
      int t2 = c * 256 + t;
      int r = t2 >> 2;
      int G = (t2 & 3) ^ (r & 3);
      gl_lds16(A + (size_t)(m0 + r) * K + k0 + G * 8, &As[sb][(size_t)(c * 256 + wave * 64) * 8]);
      gl_lds16(Bt + (size_t)(n0 + r) * K + k0 + G * 8, &Bs[sb][(size_t)(c * 256 + wave * 64) * 8]);
    }
  };

  stage(0, 0);
  __syncthreads();

  int nsteps = K >> 5;
  for (int s = 0; s < nsteps; s++) {
    int cur = s & 1;
    if (s + 1 < nsteps) stage((s + 1) << 5, cur ^ 1);
    bf16x8 af[4], bf[4];
#pragma unroll
    for (int i = 0; i < 4; i++) {
      af[i] = *(const bf16x8*)&As[cur][(wm + i * 16 + m15) * 32 + gsw];
      bf[i] = *(const bf16x8*)&Bs[cur][(wn + i * 16 + m15) * 32 + gsw];
    }
#pragma unroll
    for (int mi = 0; mi < 4; mi++)
#pragma unroll
      for (int ni = 0; ni < 4; ni++) acc[mi][ni] = mfma16(af[mi], bf[ni], acc[mi][ni]);
    __syncthreads();
  }

  int rbase = quad * 4;
#pragma unroll
  for (int mi = 0; mi < 4; mi++) {
#pragma unroll
    for (int ni = 0; ni < 4; ni++) {
#pragma unroll
      for (int r = 0; r < 4; r++) {
        int row = m0 + wm + mi * 16 + rbase + r;
        int col = n0 + wn + ni * 16 + m15;
        float v = acc[mi][ni][r];
        if (EPI == 0) {
          outb[(size_t)row * N + col] = f2b(v);
        } else if (EPI == 1) {
          int b = row >> 12;
          size_t o = (size_t)row * E + col;
          outf[o] = resid[o] + v * alpha[b * E + col];
        } else if (EPI == 2) {
          v += bias[col];
          outb[(size_t)row * N + col] = f2b(v > 0.f ? v : 0.f);
        } else {
          int b = row >> 12;
          size_t o = (size_t)row * E + col;
          outf[o] = outf[o] + (v + bias[col]) * alpha[b * E + col];
        }
      }
    }
  }
}

// ---------------- bf16 MFMA GEMM, 64x128 tile, double-buffered ----------------
template <int EPI>
__global__ __launch_bounds__(256) void gemm64(
    const unsigned short* __restrict__ A, const unsigned short* __restrict__ Bt,
    const float* __restrict__ bias, const float* __restrict__ alpha,
    const float* __restrict__ resid, float* __restrict__ outf,
    unsigned short* __restrict__ outb, int N, int K) {
  __shared__ __align__(16) unsigned short As[2][64 * 32];
  __shared__ __align__(16) unsigned short Bs[2][128 * 32];
  int t = threadIdx.x, lane = t & 63, wave = t >> 6;
  int m0 = blockIdx.y * 64, n0 = blockIdx.x * 128;
  int m15 = lane & 15, quad = lane >> 4;

  floatx4 acc[4][2];
  floatx4 vz = {0.f, 0.f, 0.f, 0.f};
#pragma unroll
  for (int i = 0; i < 4; i++)
#pragma unroll
    for (int j = 0; j < 2; j++) acc[i][j] = vz;

  int wn = wave * 32;
  int gsw = (quad ^ (m15 & 3)) * 8;

  auto stage = [&](int k0, int sb) {
    {
      int r = t >> 2;
      int G = (t & 3) ^ (r & 3);
      gl_lds16(A + (size_t)(m0 + r) * K + k0 + G * 8, &As[sb][(size_t)(wave * 64) * 8]);
    }
#pragma unroll
    for (int c = 0; c < 2; c++) {
      int t2 = c * 256 + t;
      int r = t2 >> 2;
      int G = (t2 & 3) ^ (r & 3);
      gl_lds16(Bt + (size_t)(n0 + r) * K + k0 + G * 8, &Bs[sb][(size_t)(c * 256 + wave * 64) * 8]);
    }
  };

  stage(0, 0);
  __syncthreads();

  int nsteps = K >> 5;
  for (int s = 0; s < nsteps; s++) {
    int cur = s & 1;
    if (s + 1 < nsteps) stage((s + 1) << 5, cur ^ 1);
    bf16x8 af[4], bf[2];
#pragma unroll
    for (int i = 0; i < 4; i++) af[i] = *(const bf16x8*)&As[cur][(i * 16 + m15) * 32 + gsw];
#pragma unroll
    for (int j = 0; j < 2; j++) bf[j] = *(const bf16x8*)&Bs[cur][(wn + j * 16 + m15) * 32 + gsw];
#pragma unroll
    for (int mi = 0; mi < 4; mi++)
#pragma unroll
      for (int ni = 0; ni < 2; ni++) acc[mi][ni] = mfma16(af[mi], bf[ni], acc[mi][ni]);
    __syncthreads();
  }

  int rbase = quad * 4;
#pragma unroll
  for (int mi = 0; mi < 4; mi++) {
#pragma unroll
    for (int ni = 0; ni < 2; ni++) {
#pragma unroll
      for (int r = 0; r < 4; r++) {
        int row = m0 + mi * 16 + rbase + r;
        int col = n0 + wn + ni * 16 + m15;
        float v = acc[mi][ni][r];
        if (EPI == 1) {
          int b = row >> 12;
          size_t o = (size_t)row * E + col;
          outf[o] = resid[o] + v * alpha[b * E + col];
        } else {
          int b = row >> 12;
          size_t o = (size_t)row * E + col;
          outf[o] = outf[o] + (v + bias[col]) * alpha[b * E + col];
        }
      }
    }
  }
}

// ---------------- flash attention v7: shuffle-free PV via 16x16x16 MFMA ----------
// v5 base (dbuf K/V, 48KB LDS, grid=768=3 blocks/CU). S^T = K Q^T (x32 MFMA).
// exp'd S^T C-layout (key=quad*4+r, q=m15) IS the x16 MFMA B-operand layout
// (k=quad*4+i, n=m15) -> PV runs directly on it: O^T[d][q] += V^T A-frag x P B-frag.
// V^T A-frags are ds_read_b64 (4 keys/lane) from the swizzled Vt layout; the old
// 32 ds_bpermute + select transpose per tile-wave is deleted.
__global__ __launch_bounds__(256) void flash_attn(const unsigned short* __restrict__ qkv,
                                                  unsigned short* __restrict__ outb) {
  __shared__ __align__(16) unsigned short Qs[128 * 64];
  __shared__ __align__(16) unsigned short Ks[2][64 * 64];
  __shared__ __align__(16) unsigned short Vt[2][64 * 64];
  int t = threadIdx.x, lane = t & 63, wave = t >> 6;
  int m15 = lane & 15, quad = lane >> 4;
  int q0 = blockIdx.x * 128;
  int bh = blockIdx.y;
  int b = bh / NHEAD, h = bh - b * NHEAD;
  const unsigned short* qp = qkv + (size_t)b * SEQ * QKVN + h * HD;
  const unsigned short* kp = qp + E;
  const unsigned short* vp = qp + 2 * E;
  int kpr = t & 31, dg = t >> 5;

#pragma unroll
  for (int c = 0; c < 4; c++) {
    int slot = c * 256 + t;
    int qr = slot >> 3, s = slot & 7;
    int g = s ^ (qr & 7);
    gl_lds16(qp + (size_t)(q0 + qr) * QKVN + g * 8, Qs + (size_t)(c * 256 + wave * 64) * 8);
  }

  auto stageK = [&](int kb0, unsigned short* Kbuf) {
#pragma unroll
    for (int c = 0; c < 2; c++) {
      int slot = c * 256 + t;
      int kr = slot >> 3, s = slot & 7;
      int g = s ^ (kr & 7);
      gl_lds16(kp + (size_t)(kb0 + kr) * QKVN + g * 8, Kbuf + (size_t)(c * 256 + wave * 64) * 8);
    }
  };
  auto loadV = [&](int kb0, int4& r0, int4& r1) {
    r0 = *(const int4*)(vp + (size_t)(kb0 + 2 * kpr) * QKVN + dg * 8);
    r1 = *(const int4*)(vp + (size_t)(kb0 + 2 * kpr + 1) * QKVN + dg * 8);
  };
  auto writeVt = [&](unsigned short* Vbuf, int4 r0, int4 r1) {
    const unsigned short* u0 = (const unsigned short*)&r0;
    const unsigned short* u1 = (const unsigned short*)&r1;
    int kg = kpr >> 2, pos = kpr & 3;
    unsigned int* V32 = (unsigned int*)Vbuf;
#pragma unroll
    for (int i = 0; i < 8; i++) {
      int d = dg * 8 + i;
      V32[d * 32 + ((kg ^ i ^ dg) & 7) * 4 + pos] =
          (unsigned int)u0[i] | ((unsigned int)u1[i] << 16);
    }
  };

  stageK(0, Ks[0]);
  int4 va, vb;
  loadV(0, va, vb);
  writeVt(Vt[0], va, vb);
  __syncthreads();

  const float QSCALE = 0.125f * 1.44269504f;
  bf16x8 qf[2][2];
#pragma unroll
  for (int mt = 0; mt < 2; mt++) {
    int qr = wave * 32 + mt * 16 + m15;
#pragma unroll
    for (int dh = 0; dh < 2; dh++) {
      bf16x8 v = *(const bf16x8*)&Qs[qr * 64 + (((dh * 4 + quad) ^ (m15 & 7)) * 8)];
#pragma unroll
      for (int i = 0; i < 8; i++) v[i] = (__bf16)((float)v[i] * QSCALE);
      qf[mt][dh] = v;
    }
  }

  float lsum[2] = {0.f, 0.f};
  floatx4 of[2][4];
  floatx4 vz = {0.f, 0.f, 0.f, 0.f};
#pragma unroll
  for (int mt = 0; mt < 2; mt++)
#pragma unroll
    for (int dt = 0; dt < 4; dt++) of[mt][dt] = vz;

  int buf = 0;
  for (int kb0 = 0; kb0 < SEQ; kb0 += 64) {
    // K frags for QK^T (b128)
    bf16x8 kf[4][2];
#pragma unroll
    for (int kt = 0; kt < 4; kt++)
#pragma unroll
      for (int dh = 0; dh < 2; dh++)
        kf[kt][dh] =
            *(const bf16x8*)&Ks[buf][(kt * 16 + m15) * 64 + (((dh * 4 + quad) ^ (m15 & 7)) * 8)];
    // V^T A-frags for x16 PV (b64: 4 keys per lane, k=quad*4+i)
    short4v vf64[4][4];
#pragma unroll
    for (int dt = 0; dt < 4; dt++) {
      int d = dt * 16 + m15;
      int sw = (d & 7) ^ (d >> 3);
#pragma unroll
      for (int kt = 0; kt < 4; kt++) {
        int slot = ((kt * 2 + (quad >> 1)) ^ sw) & 7;
        vf64[dt][kt] = *(const short4v*)&Vt[buf][d * 64 + slot * 8 + (quad & 1) * 4];
      }
    }

    int nkb = (kb0 + 64) & (SEQ - 1);
    stageK(nkb, Ks[buf ^ 1]);
    loadV(nkb, va, vb);

#pragma unroll
    for (int mt = 0; mt < 2; mt++) {
      // S^T = K Q^T : lane holds S[key=kt*16+quad*4+r][q=m15]
      floatx4 st[4];
#pragma unroll
      for (int kt = 0; kt < 4; kt++) {
        st[kt] = vz;
#pragma unroll
        for (int dh = 0; dh < 2; dh++) st[kt] = mfma16(kf[kt][dh], qf[mt][dh], st[kt]);
      }
      // exp2 (no max); bf16 pack = x16 B-frag directly; per-lane partial l
      short4v pb[4];
      float lp = 0.f;
#pragma unroll
      for (int kt = 0; kt < 4; kt++) {
        floatx4 p;
#pragma unroll
        for (int r = 0; r < 4; r++) {
          p[r] = __builtin_amdgcn_exp2f(st[kt][r]);
          lp += p[r];
        }
        pb[kt] = __builtin_bit_cast(short4v, __builtin_convertvector(p, bf16x4));
      }
      lsum[mt] += lp;

      // O^T += V^T P^T  (16 x16-MFMAs, no cross-lane movement)
#pragma unroll
      for (int kt = 0; kt < 4; kt++)
#pragma unroll
        for (int dt = 0; dt < 4; dt++)
          of[mt][dt] = mfma16k16(vf64[dt][kt], pb[kt], of[mt][dt]);
    }

    writeVt(Vt[buf ^ 1], va, vb);
    __syncthreads();
    buf ^= 1;
  }

#pragma unroll
  for (int mt = 0; mt < 2; mt++) {
    lsum[mt] += __shfl_xor(lsum[mt], 16, 64);
    lsum[mt] += __shfl_xor(lsum[mt], 32, 64);
    float inv = 1.f / lsum[mt];
    int q = q0 + wave * 32 + mt * 16 + m15;
    unsigned short* orow = outb + (size_t)(b * SEQ + q) * E + h * HD;
#pragma unroll
    for (int dt = 0; dt < 4; dt++) {
      floatx4 o;
#pragma unroll
      for (int r = 0; r < 4; r++) o[r] = of[mt][dt][r] * inv;
      bf16x4 ob = __builtin_convertvector(o, bf16x4);
      *(uintx2*)&orow[dt * 16 + quad * 4] = __builtin_bit_cast(uintx2, ob);
    }
  }
}

extern "C" void kernel_launch(void* const* d_in, const int* in_sizes, int n_in,
                              void* d_out, int out_size, void* d_ws, size_t ws_size,
                              hipStream_t stream) {
  const float* x     = (const float*)d_in[0];
  const float* cond  = (const float*)d_in[1];
  const float* g1_w  = (const float*)d_in[2];  const float* g1_b  = (const float*)d_in[3];
  const float* be1_w = (const float*)d_in[4];  const float* be1_b = (const float*)d_in[5];
  const float* a1_w  = (const float*)d_in[6];  const float* a1_b  = (const float*)d_in[7];
  const float* g2_w  = (const float*)d_in[8];  const float* g2_b  = (const float*)d_in[9];
  const float* be2_w = (const float*)d_in[10]; const float* be2_b = (const float*)d_in[11];
  const float* a2_w  = (const float*)d_in[12]; const float* a2_b  = (const float*)d_in[13];
  const float* ln1_w = (const float*)d_in[14]; const float* ln1_b = (const float*)d_in[15];
  const float* ln2_w = (const float*)d_in[16]; const float* ln2_b = (const float*)d_in[17];
  const float* wq    = (const float*)d_in[18]; const float* wk    = (const float*)d_in[19];
  const float* wv    = (const float*)d_in[20]; const float* wo    = (const float*)d_in[21];
  const float* ff1_w = (const float*)d_in[22]; const float* ff1_b = (const float*)d_in[23];
  const float* ff2_w = (const float*)d_in[24]; const float* ff2_b = (const float*)d_in[25];
  float* out = (float*)d_out;

  char* ws = (char*)d_ws;
  size_t off = 0;
  auto alloc = [&](size_t bytes) -> void* {
    void* p = ws + off;
    off += (bytes + 255) & ~(size_t)255;
    return p;
  };
  float* condp            = (float*)alloc((size_t)6 * BATCH * E * 4);
  unsigned short* wqkv_t  = (unsigned short*)alloc((size_t)QKVN * E * 2);
  unsigned short* wo_t    = (unsigned short*)alloc((size_t)E * E * 2);
  unsigned short* ff1_t   = (unsigned short*)alloc((size_t)FFH * E * 2);
  unsigned short* ff2_t   = (unsigned short*)alloc((size_t)E * FFH * 2);
  unsigned short* ymod    = (unsigned short*)alloc((size_t)M_TOK * E * 2);
  unsigned short* qkvbuf  = (unsigned short*)alloc((size_t)M_TOK * QKVN * 2);
  unsigned short* attnout = (unsigned short*)alloc((size_t)M_TOK * E * 2);
  unsigned short* hbuf    = (unsigned short*)alloc((size_t)M_TOK * FFH * 2);

  float* gamma1 = condp;            float* beta1 = condp + 1536;
  float* alpha1 = condp + 3072;     float* gamma2 = condp + 4608;
  float* beta2 = condp + 6144;      float* alpha2 = condp + 7680;

  prep_weights<<<6912, 256, 0, stream>>>(wq, wk, wv, wo, ff1_w, ff2_w,
                                         wqkv_t, wo_t, ff1_t, ff2_t, condp);
  cond_proj<<<144, 256, 0, stream>>>(cond, g1_w, g1_b, be1_w, be1_b, a1_w, a1_b,
                                     g2_w, g2_b, be2_w, be2_b, a2_w, a2_b, condp);
  ln_mod<<<4096, 256, 0, stream>>>(x, ln1_w, ln1_b, gamma1, beta1, ymod);
  gemm_bt<0><<<dim3(QKVN / 128, M_TOK / 128), 256, 0, stream>>>(
      ymod, wqkv_t, nullptr, nullptr, nullptr, nullptr, qkvbuf, QKVN, E);
  flash_attn<<<dim3(SEQ / 128, BATCH * NHEAD), 256, 0, stream>>>(qkvbuf, attnout);
  gemm64<1><<<dim3(E / 128, M_TOK / 64), 256, 0, stream>>>(
      attnout, wo_t, nullptr, alpha1, x, out, nullptr, E, E);
  ln_mod<<<4096, 256, 0, stream>>>(out, ln2_w, ln2_b, gamma2, beta2, ymod);
  gemm_bt<2><<<dim3(FFH / 128, M_TOK / 128), 256, 0, stream>>>(
      ymod, ff1_t, ff1_b, nullptr, nullptr, nullptr, hbuf, FFH, E);
  gemm64<3><<<dim3(E / 128, M_TOK / 64), 256, 0, stream>>>(
      hbuf, ff2_t, ff2_b, alpha2, nullptr, out, nullptr, E, FFH);
}